// Round 9
// baseline (873.123 us; speedup 1.0000x reference)
//
#include <hip/hip_runtime.h>
#include <math.h>

#define NN 100000
#define NE 1000000
#define DH 64
#define DIN 128
#define DOUT 40
#define NL 7
#define SCAN_B 1024
#define NBLK ((NN + SCAN_B - 1) / SCAN_B)  // 98
#define NGRP (NN / 16)     // 6250 16-node groups (exact)
#define LBLK ((NGRP + 3) / 4)
#define COLB_CAP (NE + 16 * NN + 64)  // padded CSR capacity (entries)

typedef _Float16 v8h __attribute__((ext_vector_type(8)));
typedef _Float16 v2h __attribute__((ext_vector_type(2)));
typedef float v4f __attribute__((ext_vector_type(4)));

__device__ __forceinline__ float lane_bcast(float v, int l) {
  return __int_as_float(__builtin_amdgcn_readlane(__float_as_int(v), l));
}

// ---------------- CSR build ----------------
__global__ __launch_bounds__(256) void k_count(const int* __restrict__ dst,
                                               int* __restrict__ cnt) {
  int i = blockIdx.x * 256 + threadIdx.x;
  if (i < NE) atomicAdd(&cnt[dst[i]], 1);
}

// exclusive scan over PADDED counts: ceil16(cnt[i])
__global__ __launch_bounds__(SCAN_B) void k_scan1(const int* __restrict__ cnt,
                                                  int* __restrict__ rp16,
                                                  int* __restrict__ bsum) {
  __shared__ int buf[SCAN_B];
  int i = blockIdx.x * SCAN_B + threadIdx.x;
  int v = (i < NN) ? ((cnt[i] + 15) & ~15) : 0;
  buf[threadIdx.x] = v;
  __syncthreads();
  for (int off = 1; off < SCAN_B; off <<= 1) {
    int t = (threadIdx.x >= off) ? buf[threadIdx.x - off] : 0;
    __syncthreads();
    buf[threadIdx.x] += t;
    __syncthreads();
  }
  if (i < NN) rp16[i] = buf[threadIdx.x] - v;
  if (threadIdx.x == SCAN_B - 1) bsum[blockIdx.x] = buf[SCAN_B - 1];
}

__global__ __launch_bounds__(128) void k_scan2(int* __restrict__ bsum) {
  __shared__ int buf[128];
  int v = (threadIdx.x < NBLK) ? bsum[threadIdx.x] : 0;
  buf[threadIdx.x] = v;
  __syncthreads();
  for (int off = 1; off < 128; off <<= 1) {
    int t = (threadIdx.x >= off) ? buf[threadIdx.x - off] : 0;
    __syncthreads();
    buf[threadIdx.x] += t;
    __syncthreads();
  }
  if (threadIdx.x < NBLK) bsum[threadIdx.x] = buf[threadIdx.x] - v;
}

__global__ __launch_bounds__(SCAN_B) void k_scan3(int* __restrict__ rp16,
                                                  int* __restrict__ cur,
                                                  const int* __restrict__ bsum) {
  int i = blockIdx.x * SCAN_B + threadIdx.x;
  if (i < NN) {
    int rp = rp16[i] + bsum[blockIdx.x];
    rp16[i] = rp;
    cur[i] = rp;
  }
}

// colb stores BYTE offsets into the f16 msg array: src * DH * 2
__global__ __launch_bounds__(256) void k_scatter(const int* __restrict__ src,
                                                 const int* __restrict__ dst,
                                                 int* __restrict__ cur,
                                                 int* __restrict__ colb) {
  int i = blockIdx.x * 256 + threadIdx.x;
  if (i < NE) {
    int d = dst[i];
    int p = atomicAdd(&cur[d], 1);
    colb[p] = src[i] * (DH * 2);
  }
}

// ---------------- Encoder: h = x @ W_enc + b_enc ----------------
__global__ __launch_bounds__(256) void k_encoder(const float* __restrict__ x,
                                                 const float* __restrict__ W,
                                                 const float* __restrict__ b,
                                                 float* __restrict__ h) {
  int lane = threadIdx.x & 63;
  float wc[DIN];
#pragma unroll
  for (int k = 0; k < DIN; ++k) wc[k] = W[k * DH + lane];
  float bj = b[lane];
  int wid = (blockIdx.x * blockDim.x + threadIdx.x) >> 6;
  int nw = (gridDim.x * blockDim.x) >> 6;
  for (int n = wid; n < NN; n += nw) {
    float v0 = x[n * DIN + lane];
    float v1 = x[n * DIN + 64 + lane];
    float acc = bj;
#pragma unroll
    for (int k = 0; k < 64; ++k) acc = fmaf(lane_bcast(v0, k), wc[k], acc);
#pragma unroll
    for (int k = 0; k < 64; ++k) acc = fmaf(lane_bcast(v1, k), wc[64 + k], acc);
    h[n * DH + lane] = acc;
  }
}

// ---------------- Message precompute: msg = f16(relu(bn(h)) + eps) ----------------
__global__ __launch_bounds__(256) void k_msg(const float* __restrict__ h,
                                             const float* __restrict__ stats_in,
                                             const float* __restrict__ gamma,
                                             const float* __restrict__ beta,
                                             _Float16* __restrict__ msg) {
  int lane = threadIdx.x & 63;
  float scale = 1.f, shift = 0.f;
  if (stats_in) {
    float mu = stats_in[lane] * (1.0f / NN);
    float var = stats_in[64 + lane] * (1.0f / NN) - mu * mu;
    scale = gamma[lane] * rsqrtf(var + 1e-5f);
    shift = beta[lane] - mu * scale;
  }
  int wid = (blockIdx.x * blockDim.x + threadIdx.x) >> 6;
  int nw = (gridDim.x * blockDim.x) >> 6;
  for (int n = wid; n < NN; n += nw) {
    float r = h[n * DH + lane];
    float v = fmaxf(fmaf(r, scale, shift), 0.f) + 1e-7f;
    msg[n * DH + lane] = (_Float16)v;
  }
}

// ---------------- Gather + segment softmax agg: one wave per node ----------------
// lane = (f2 = feature pair 0..31, ep = edge parity). 16 padded edges/round:
// 4x int4 col loads (one 64B line) + 8x 4B gathers (2 edges in flight per pair).
__global__ __launch_bounds__(256, 8) void k_agg(const _Float16* __restrict__ msg,
                                                const int* __restrict__ rp16,
                                                const int* __restrict__ cnt,
                                                const int* __restrict__ colb,
                                                _Float16* __restrict__ agg) {
  const int lane = threadIdx.x & 63;
  const int f2 = lane & 31;
  const int ep = lane >> 5;
  const int n = (blockIdx.x * 256 + threadIdx.x) >> 6;  // exact: NN*64 == grid*256
  const int beg = rp16[n];
  const int deg = cnt[n];
  const char* mb = (const char*)msg + 4 * f2;
  float s0 = 0.f, s1 = 0.f, t0 = 0.f, t1 = 0.f;
  for (int j = 0; j < deg; j += 16) {
    const int4* cp = (const int4*)(colb + beg + j);  // 64B-aligned (beg%16==0)
    int4 q0 = cp[0], q1 = cp[1], q2 = cp[2], q3 = cp[3];
    int rem = deg - j;  // wave-uniform
    int o0 = ep ? q0.y : q0.x, o1 = ep ? q0.w : q0.z;
    int o2 = ep ? q1.y : q1.x, o3 = ep ? q1.w : q1.z;
    int o4 = ep ? q2.y : q2.x, o5 = ep ? q2.w : q2.z;
    int o6 = ep ? q3.y : q3.x, o7 = ep ? q3.w : q3.z;
    v2h g0 = *(const v2h*)(mb + o0);
    v2h g1 = *(const v2h*)(mb + o1);
    v2h g2 = *(const v2h*)(mb + o2);
    v2h g3 = *(const v2h*)(mb + o3);
    v2h g4 = *(const v2h*)(mb + o4);
    v2h g5 = *(const v2h*)(mb + o5);
    v2h g6 = *(const v2h*)(mb + o6);
    v2h g7 = *(const v2h*)(mb + o7);
#define PAIR_ACC(P, G)                                      \
    {                                                       \
      float vlo = (float)G.x, vhi = (float)G.y;             \
      float m = (2 * P + ep < rem) ? 1.f : 0.f;             \
      float elo = __expf(vlo) * m, ehi = __expf(vhi) * m;   \
      s0 += elo; t0 = fmaf(elo, vlo, t0);                   \
      s1 += ehi; t1 = fmaf(ehi, vhi, t1);                   \
    }
    PAIR_ACC(0, g0) PAIR_ACC(1, g1) PAIR_ACC(2, g2) PAIR_ACC(3, g3)
    PAIR_ACC(4, g4) PAIR_ACC(5, g5) PAIR_ACC(6, g6) PAIR_ACC(7, g7)
#undef PAIR_ACC
  }
  // combine the two edge-parity halves (lanes L and L^32 share features)
  s0 += __shfl_xor(s0, 32, 64); t0 += __shfl_xor(t0, 32, 64);
  s1 += __shfl_xor(s1, 32, 64); t1 += __shfl_xor(t1, 32, 64);
  if (ep == 0) {
    v2h r;
    r.x = (_Float16)(t0 / (s0 + 1e-16f));
    r.y = (_Float16)(t1 / (s1 + 1e-16f));
    *(v2h*)((char*)agg + (size_t)n * 128 + 4 * f2) = r;
  }
}

// ---------------- MFMA layer: combine(h,agg) -> GEMM (+bias,+res) -> col-stats
//                  One wave = 16 contiguous nodes. ----------------
__global__ __launch_bounds__(256) void k_mfma(
    const float* __restrict__ h_pre, const _Float16* __restrict__ agg,
    const float* __restrict__ stats_in,
    const float* __restrict__ gamma, const float* __restrict__ beta,
    const float* __restrict__ W, const float* __restrict__ b, int add_res,
    float* __restrict__ hout, float* __restrict__ stats_out) {
  __shared__ _Float16 Atile[4][1024];  // per-wave swizzled 16x64 f16 A-tile (8 KB)
  const int tid = threadIdx.x;
  const int w = tid >> 6, lane = tid & 63;
  const int gid = blockIdx.x * 4 + w;
  const int row = lane & 15, hi = lane >> 4;

  float ss0 = 0, ss1 = 0, ss2 = 0, ss3 = 0;
  float qq0 = 0, qq1 = 0, qq2 = 0, qq3 = 0;

  if (gid < NGRP) {  // wave-uniform
    float scale = 1.f, shift = 0.f;
    if (stats_in) {
      float mu = stats_in[lane] * (1.0f / NN);
      float var = stats_in[64 + lane] * (1.0f / NN) - mu * mu;
      scale = gamma[lane] * rsqrtf(var + 1e-5f);
      shift = beta[lane] - mu * scale;
    }
    // B fragments of W (64x64, row-major [k][n]) in f16:
    // lane holds k = kt*32 + hi*8 + j, n = ct*16 + row
    v8h bf[2][4];
#pragma unroll
    for (int kt = 0; kt < 2; ++kt)
#pragma unroll
      for (int ct = 0; ct < 4; ++ct)
#pragma unroll
        for (int j = 0; j < 8; ++j)
          bf[kt][ct][j] = (_Float16)W[(kt * 32 + hi * 8 + j) * DH + ct * 16 + row];

    const int base = gid * 16;
    const float* hl = h_pre + lane;
    const _Float16* agl = agg + lane;
    _Float16* At = &Atile[w][0];

#pragma unroll 4
    for (int i = 0; i < 16; ++i) {
      size_t o = (size_t)(base + i) * DH;
      float raw = hl[o];
      float ag = (float)agl[o];
      float v = stats_in ? fmaxf(fmaf(raw, scale, shift), 0.f) : raw;
      v += ag;
      // swizzled write: row i, feature lane (byte col 2*lane)
      At[(i * 128 + ((lane * 2) ^ ((i & 7) << 4))) >> 1] = (_Float16)v;
    }

    // A fragments: lane reads row=(lane&15), k = kt*32 + hi*8 + j (16B swizzle-stable)
    const int sw = (row & 7) << 4;
    v8h a0 = *(const v8h*)&At[((row * 128) + ((hi * 16) ^ sw)) >> 1];
    v8h a1 = *(const v8h*)&At[((row * 128) + ((64 + hi * 16) ^ sw)) >> 1];
    v4f c0 = {0, 0, 0, 0}, c1 = {0, 0, 0, 0}, c2 = {0, 0, 0, 0}, c3 = {0, 0, 0, 0};
    c0 = __builtin_amdgcn_mfma_f32_16x16x32_f16(a0, bf[0][0], c0, 0, 0, 0);
    c0 = __builtin_amdgcn_mfma_f32_16x16x32_f16(a1, bf[1][0], c0, 0, 0, 0);
    c1 = __builtin_amdgcn_mfma_f32_16x16x32_f16(a0, bf[0][1], c1, 0, 0, 0);
    c1 = __builtin_amdgcn_mfma_f32_16x16x32_f16(a1, bf[1][1], c1, 0, 0, 0);
    c2 = __builtin_amdgcn_mfma_f32_16x16x32_f16(a0, bf[0][2], c2, 0, 0, 0);
    c2 = __builtin_amdgcn_mfma_f32_16x16x32_f16(a1, bf[1][2], c2, 0, 0, 0);
    c3 = __builtin_amdgcn_mfma_f32_16x16x32_f16(a0, bf[0][3], c3, 0, 0, 0);
    c3 = __builtin_amdgcn_mfma_f32_16x16x32_f16(a1, bf[1][3], c3, 0, 0, 0);

    // epilogue in C layout: col = ct*16 + row, node = base + hi*4 + reg
    float b0 = b[row], b1 = b[16 + row], b2 = b[32 + row], b3 = b[48 + row];
#pragma unroll
    for (int reg = 0; reg < 4; ++reg) {
      size_t o = (size_t)(base + hi * 4 + reg) * DH;
      float a0v = c0[reg] + b0;
      float a1v = c1[reg] + b1;
      float a2v = c2[reg] + b2;
      float a3v = c3[reg] + b3;
      if (add_res) {
        a0v += h_pre[o + row];
        a1v += h_pre[o + 16 + row];
        a2v += h_pre[o + 32 + row];
        a3v += h_pre[o + 48 + row];
      }
      hout[o + row] = a0v;
      hout[o + 16 + row] = a1v;
      hout[o + 32 + row] = a2v;
      hout[o + 48 + row] = a3v;
      ss0 += a0v; qq0 = fmaf(a0v, a0v, qq0);
      ss1 += a1v; qq1 = fmaf(a1v, a1v, qq1);
      ss2 += a2v; qq2 = fmaf(a2v, a2v, qq2);
      ss3 += a3v; qq3 = fmaf(a3v, a3v, qq3);
    }
  }

  // reduce across the 4 row-groups (lanes l, l^16, l^32 share column)
#pragma unroll
  for (int off = 16; off <= 32; off <<= 1) {
    ss0 += __shfl_xor(ss0, off, 64); ss1 += __shfl_xor(ss1, off, 64);
    ss2 += __shfl_xor(ss2, off, 64); ss3 += __shfl_xor(ss3, off, 64);
    qq0 += __shfl_xor(qq0, off, 64); qq1 += __shfl_xor(qq1, off, 64);
    qq2 += __shfl_xor(qq2, off, 64); qq3 += __shfl_xor(qq3, off, 64);
  }
  __syncthreads();  // done with f16 A-tiles; reuse LDS as float scratch
  float* Sr = (float*)&Atile[0][0];
  if (lane < 16) {
    Sr[w * 128 + lane] = ss0;       Sr[w * 128 + 16 + lane] = ss1;
    Sr[w * 128 + 32 + lane] = ss2;  Sr[w * 128 + 48 + lane] = ss3;
    Sr[w * 128 + 64 + lane] = qq0;  Sr[w * 128 + 80 + lane] = qq1;
    Sr[w * 128 + 96 + lane] = qq2;  Sr[w * 128 + 112 + lane] = qq3;
  }
  __syncthreads();
  if (tid < 128) {
    float vsum = Sr[tid] + Sr[128 + tid] + Sr[256 + tid] + Sr[384 + tid];
    atomicAdd(&stats_out[tid], vsum);
  }
}

// ---------------- Final BN+ReLU + prediction head + log_softmax ----------------
__global__ __launch_bounds__(256) void k_pred(
    const float* __restrict__ h_pre, const float* __restrict__ stats_in,
    const float* __restrict__ gamma, const float* __restrict__ beta,
    const float* __restrict__ Wp, const float* __restrict__ bp,
    float* __restrict__ out) {
  int lane = threadIdx.x & 63;
  float mu = stats_in[lane] * (1.0f / NN);
  float var = stats_in[64 + lane] * (1.0f / NN) - mu * mu;
  float scale = gamma[lane] * rsqrtf(var + 1e-5f);
  float shift = beta[lane] - mu * scale;
  int lc = lane < DOUT ? lane : DOUT - 1;
  float wc[DH];
#pragma unroll
  for (int k = 0; k < DH; ++k) wc[k] = Wp[k * DOUT + lc];
  float bj = bp[lc];
  int wid = (blockIdx.x * blockDim.x + threadIdx.x) >> 6;
  int nw = (gridDim.x * blockDim.x) >> 6;
  for (int n = wid; n < NN; n += nw) {
    float raw = h_pre[n * DH + lane];
    float v = fmaxf(fmaf(raw, scale, shift), 0.f);
    float acc = bj;
#pragma unroll
    for (int k = 0; k < DH; ++k) acc = fmaf(lane_bcast(v, k), wc[k], acc);
    float xm = (lane < DOUT) ? acc : -INFINITY;
#pragma unroll
    for (int o = 32; o >= 1; o >>= 1) xm = fmaxf(xm, __shfl_xor(xm, o, 64));
    float e = (lane < DOUT) ? __expf(acc - xm) : 0.f;
#pragma unroll
    for (int o = 32; o >= 1; o >>= 1) e += __shfl_xor(e, o, 64);
    if (lane < DOUT) out[n * DOUT + lane] = acc - xm - __logf(e);
  }
}

extern "C" void kernel_launch(void* const* d_in, const int* in_sizes, int n_in,
                              void* d_out, int out_size, void* d_ws, size_t ws_size,
                              hipStream_t stream) {
  const float* x      = (const float*)d_in[0];
  const int*   ei     = (const int*)d_in[1];
  const float* W_enc  = (const float*)d_in[2];
  const float* b_enc  = (const float*)d_in[3];
  const float* Wg     = (const float*)d_in[4];
  const float* bg     = (const float*)d_in[5];
  const float* gamma  = (const float*)d_in[6];
  const float* beta   = (const float*)d_in[7];
  const float* W_pred = (const float*)d_in[8];
  const float* b_pred = (const float*)d_in[9];
  float* out = (float*)d_out;

  const int* src = ei;
  const int* dst = ei + NE;

  char* p = (char*)d_ws;
  auto alloc = [&](size_t bytes) -> void* {
    void* r = (void*)p;
    p += (bytes + 255) & ~(size_t)255;
    return r;
  };
  float*     hA      = (float*)alloc((size_t)NN * DH * 4);
  float*     hB      = (float*)alloc((size_t)NN * DH * 4);
  _Float16*  msg     = (_Float16*)alloc((size_t)NN * DH * 2);
  _Float16*  agg     = (_Float16*)alloc((size_t)NN * DH * 2);
  int*       rp16    = (int*)alloc((size_t)(NN + 1) * 4);
  int*       cur     = (int*)alloc((size_t)NN * 4);
  int*       cnt     = (int*)alloc((size_t)NN * 4);
  int*       colb    = (int*)alloc((size_t)COLB_CAP * 4);
  int*       bsum    = (int*)alloc((size_t)NBLK * 4);
  float*     stats   = (float*)alloc((size_t)NL * 128 * 4);

  hipMemsetAsync(cnt, 0, (size_t)NN * 4, stream);
  hipMemsetAsync(stats, 0, (size_t)NL * 128 * 4, stream);
  hipMemsetAsync(colb, 0, (size_t)COLB_CAP * 4, stream);  // pads -> row 0 (masked)

  // ---- CSR build (16-padded segments) ----
  k_count<<<(NE + 255) / 256, 256, 0, stream>>>(dst, cnt);
  k_scan1<<<NBLK, SCAN_B, 0, stream>>>(cnt, rp16, bsum);
  k_scan2<<<1, 128, 0, stream>>>(bsum);
  k_scan3<<<NBLK, SCAN_B, 0, stream>>>(rp16, cur, bsum);
  k_scatter<<<(NE + 255) / 256, 256, 0, stream>>>(src, dst, cur, colb);

  // ---- Encoder ----
  k_encoder<<<1024, 256, 0, stream>>>(x, W_enc, b_enc, hA);

  const int MSG_BLOCKS = 1024;
  const int AGG_BLOCKS = NN * 64 / 256;  // one wave per node

  // ---- Layer 0 (no BN; combine uses raw h; msg = relu(h)+eps) ----
  k_msg<<<MSG_BLOCKS, 256, 0, stream>>>(hA, nullptr, nullptr, nullptr, msg);
  k_agg<<<AGG_BLOCKS, 256, 0, stream>>>(msg, rp16, cnt, colb, agg);
  k_mfma<<<LBLK, 256, 0, stream>>>(
      hA, agg, nullptr, nullptr, nullptr, Wg, bg, 0, hB, stats);

  float* h = hB;
  float* hn = hA;
  for (int l = 1; l < NL; ++l) {
    const float* st = stats + (size_t)(l - 1) * 128;
    const float* g  = gamma + (size_t)(l - 1) * DH;
    const float* be = beta + (size_t)(l - 1) * DH;
    k_msg<<<MSG_BLOCKS, 256, 0, stream>>>(h, st, g, be, msg);
    k_agg<<<AGG_BLOCKS, 256, 0, stream>>>(msg, rp16, cnt, colb, agg);
    k_mfma<<<LBLK, 256, 0, stream>>>(
        h, agg, st, g, be,
        Wg + (size_t)l * DH * DH, bg + (size_t)l * DH, 1,
        hn, stats + (size_t)l * 128);
    float* tmp = h; h = hn; hn = tmp;
  }

  // ---- Final BN + ReLU + prediction + log_softmax ----
  k_pred<<<1024, 256, 0, stream>>>(
      h, stats + (size_t)(NL - 1) * 128,
      gamma + (size_t)(NL - 1) * DH, beta + (size_t)(NL - 1) * DH,
      W_pred, b_pred, out);
}